// Round 1
// baseline (174.710 us; speedup 1.0000x reference)
//
#include <hip/hip_runtime.h>

#define NTOK 8192
#define DDIM 1024
#define NEXP 16
#define NPAIR 136   // E*(E+1)/2 pairs with e<=f
#define NREP 8      // s_glob replicas (atomic spread)
#define XROW 1032   // LDS x-tile row stride in floats (pad 8: 2-way alias only)
#define NBLK 1024   // fused grid size (ticket target)

// ws layout (floats): gwT4 [256*16 float4] = 16384 f | s_glob [NREP*1024] | ticket counter (1 int)
#define WS_GWT 0
#define WS_SG  16384
#define WS_CNT (WS_SG + NREP * DDIM)   // float-index 24576, used as int slot

// ---------------------------------------------------------------------------
// Prep: transpose gate_w [16][1024] -> gwT4[d4][e] (float4 over d, expert-
// contiguous) so routing reads are fully coalesced. Zeroes s_glob + ticket.
// ---------------------------------------------------------------------------
__global__ __launch_bounds__(256) void moe_prep(
    const float* __restrict__ gate_w,
    float* __restrict__ ws)
{
    const int gid = blockIdx.x * 256 + threadIdx.x;   // 0..4095
    const int e = gid & 15;
    const int d4 = gid >> 4;                          // 0..255
    const float4* gw4 = (const float4*)gate_w;
    float4* gwT4 = (float4*)(ws + WS_GWT);
    gwT4[d4 * 16 + e] = gw4[e * 256 + d4];
    float* s_glob = ws + WS_SG;
    s_glob[gid] = 0.f;
    s_glob[gid + 4096] = 0.f;
    if (gid == 0) ((int*)ws)[WS_CNT] = 0;             // ticket counter
}

// ---------------------------------------------------------------------------
// Fused: 1024 blocks x 256 thr, 8 tokens/block.
// A: x-tile -> LDS (coalesced, once); thread t owns d-cols 4t..4t+3 ->
//    x^2 column partials with no reduction needed.
// B: routing from LDS x (broadcast) + gwT (coalesced). Lane=(g tok, h half,
//    e expert): 512-d half dot, shfl_xor(16) completes logit.
// C: top2 shfl scan (stable, matches lax.top_k).
// D: combine; x from LDS, re rows L1-hot, coalesced float4 out.
// E: last-block ticket tail computes the diversity loss (replaces the old
//    moe_div_partial + moe_div_final launches). Correctness: s_glob updates
//    are device-scope L2 atomics; __syncthreads drains them (vmcnt before
//    s_barrier), ticket atomic serializes at L2, __threadfence before reads.
// ---------------------------------------------------------------------------
__global__ __launch_bounds__(256, 4) void moe_fused(
    const float* __restrict__ x,
    const float* __restrict__ gate_b,
    const float* __restrict__ sh,
    const float* __restrict__ re,
    float* __restrict__ out,
    float* __restrict__ ws)
{
    __shared__ __align__(16) float xt[8][XROW];
    __shared__ float nr[NEXP];
    __shared__ float lsum;
    __shared__ int   is_last;

    const int t = threadIdx.x;
    const int b = blockIdx.x;
    const float4* gwT4 = (const float4*)(ws + WS_GWT);
    float* s_glob = ws + WS_SG;

    // ---- A: stage 8 token rows, accumulate x^2 for owned d-columns ----
    float4 ss = make_float4(0.f, 0.f, 0.f, 0.f);
    {
        const float4* x4 = (const float4*)x + (size_t)b * 2048;
        #pragma unroll
        for (int i = 0; i < 8; ++i) {
            float4 v = x4[i * 256 + t];
            *(float4*)&xt[i][4 * t] = v;
            ss.x = fmaf(v.x, v.x, ss.x);
            ss.y = fmaf(v.y, v.y, ss.y);
            ss.z = fmaf(v.z, v.z, ss.z);
            ss.w = fmaf(v.w, v.w, ss.w);
        }
    }
    __syncthreads();

    const int lane = t & 63;
    const int wave = t >> 6;
    const int e = lane & 15;
    const int h = (lane >> 4) & 1;
    const int g = lane >> 5;

    // ---- B: routing ----
    const int tokL = wave * 2 + g;
    const float* xrow = &xt[tokL][h * 512];
    const float4* gt = gwT4 + h * 128 * 16;
    float4 a4 = make_float4(0.f, 0.f, 0.f, 0.f);
    #pragma unroll 8
    for (int i = 0; i < 128; ++i) {
        float4 xv = *(const float4*)(xrow + 4 * i);  // 4 distinct addrs, bcast
        float4 gv = gt[i * 16 + e];                  // 256B contiguous / 16 lanes
        a4.x = fmaf(xv.x, gv.x, a4.x);
        a4.y = fmaf(xv.y, gv.y, a4.y);
        a4.z = fmaf(xv.z, gv.z, a4.z);
        a4.w = fmaf(xv.w, gv.w, a4.w);
    }
    float acc = (a4.x + a4.y) + (a4.z + a4.w);
    acc += __shfl_xor(acc, 16, 64);                  // merge d-halves
    acc += gate_b[e];

    // ---- C: stable top2 scan in this token's 16 expert lanes ----
    float v0 = -3.0e38f, v1 = -3.0e38f;
    int i0 = 0, i1 = 0;
    const int base = lane & 32;
    #pragma unroll
    for (int j = 0; j < NEXP; ++j) {
        float lv = __shfl(acc, base + j, 64);
        if (lv > v0)      { v1 = v0; i1 = i0; v0 = lv; i0 = j; }
        else if (lv > v1) { v1 = lv; i1 = j; }
    }
    float ex = __expf(v1 - v0);                      // softmax denom cancels
    float w0 = 1.f / (1.f + ex);
    float w1 = ex * w0;

    // hoisted shared-expert column sum for combine slots
    float4 shs[4];
    {
        const float4* s0 = (const float4*)sh;
        const float4* s1 = (const float4*)(sh + DDIM);
        #pragma unroll
        for (int j = 0; j < 4; ++j) {
            float4 p = s0[lane + 64 * j];
            float4 q = s1[lane + 64 * j];
            shs[j] = make_float4(p.x + q.x, p.y + q.y, p.z + q.z, p.w + q.w);
        }
    }

    // ---- D: combine (x from LDS, coalesced out) ----
    #pragma unroll
    for (int tk = 0; tk < 2; ++tk) {
        const int src = tk << 5;
        float a0 = __shfl(w0, src, 64);
        float a1 = __shfl(w1, src, 64);
        int   e0 = __shfl(i0, src, 64);
        int   e1 = __shfl(i1, src, 64);
        const int tokL2 = wave * 2 + tk;
        const float4* xr = (const float4*)&xt[tokL2][0];
        const float4* r0 = (const float4*)(re + (size_t)e0 * DDIM);
        const float4* r1 = (const float4*)(re + (size_t)e1 * DDIM);
        float4* o = (float4*)(out + ((size_t)b * 8 + tokL2) * DDIM);
        #pragma unroll
        for (int j = 0; j < 4; ++j) {
            float4 xv = xr[lane + 64 * j];
            float4 b0 = r0[lane + 64 * j];
            float4 b1 = r1[lane + 64 * j];
            float4 r;
            r.x = xv.x * (shs[j].x + a0 * b0.x + a1 * b1.x);
            r.y = xv.y * (shs[j].y + a0 * b0.y + a1 * b1.y);
            r.z = xv.z * (shs[j].z + a0 * b0.z + a1 * b1.z);
            r.w = xv.w * (shs[j].w + a0 * b0.w + a1 * b1.w);
            o[lane + 64 * j] = r;
        }
    }

    // ---- x^2 partials: thread owns its 4 d-columns exclusively ----
    {
        float* rep = s_glob + (size_t)(b & (NREP - 1)) * DDIM;
        atomicAdd(&rep[4 * t + 0], ss.x);
        atomicAdd(&rep[4 * t + 1], ss.y);
        atomicAdd(&rep[4 * t + 2], ss.z);
        atomicAdd(&rep[4 * t + 3], ss.w);
    }

    // ---- E: ticket; last block computes diversity loss ----
    __syncthreads();   // drains this block's atomics (vmcnt(0) before barrier)
    if (t == 0) {
        __threadfence();
        int tk = atomicAdd((int*)ws + WS_CNT, 1);
        is_last = (tk == NBLK - 1);
    }
    __syncthreads();
    if (!is_last) return;
    __threadfence();   // acquire: L1 invalidate before reading s_glob

    float* smem = &xt[0][0];                     // xt is dead now; reuse as s_loc
    {
        const float4* sg4 = (const float4*)s_glob;
        float4 a = sg4[t];
        #pragma unroll
        for (int r = 1; r < NREP; ++r) {
            float4 v = sg4[r * 256 + t];
            a.x += v.x; a.y += v.y; a.z += v.z; a.w += v.w;
        }
        ((float4*)smem)[t] = a;                  // s_loc[4t..4t+3]
    }
    if (t == 0) lsum = 0.f;
    __syncthreads();

    float gacc = 0.f;
    int pe = 0, pf = 0;
    if (t < NPAIR) {
        int rem = t;
        while (rem >= NEXP - pe) { rem -= NEXP - pe; ++pe; }
        pf = pe + rem;
        const float4* ra = (const float4*)(re + (size_t)pe * DDIM);   // L2-hot
        const float4* rb = (const float4*)(re + (size_t)pf * DDIM);
        const float4* sl = (const float4*)smem;                       // bcast reads
        #pragma unroll 4
        for (int i = 0; i < 256; ++i) {
            float4 s = sl[i];
            float4 u = ra[i];
            float4 v = rb[i];
            gacc = fmaf(s.x * u.x, v.x, gacc);
            gacc = fmaf(s.y * u.y, v.y, gacc);
            gacc = fmaf(s.z * u.z, v.z, gacc);
            gacc = fmaf(s.w * u.w, v.w, gacc);
        }
        if (pe == pf) nr[pe] = fmaxf(sqrtf(gacc), 1e-8f);
    }
    __syncthreads();
    if (t < NPAIR && pe != pf) {
        float sim = gacc / (nr[pe] * nr[pf]);
        sim = fminf(1.f, fmaxf(-1.f, sim));
        atomicAdd(&lsum, 2.f * sim);             // LDS atomic, 120 adds
    }
    __syncthreads();
    if (t == 0)
        out[(size_t)NTOK * DDIM] = lsum / (float)(NEXP * (NEXP - 1)) * 0.1f;
}

extern "C" void kernel_launch(void* const* d_in, const int* in_sizes, int n_in,
                              void* d_out, int out_size, void* d_ws, size_t ws_size,
                              hipStream_t stream) {
    const float* x  = (const float*)d_in[0];
    const float* gw = (const float*)d_in[1];
    const float* gb = (const float*)d_in[2];
    const float* sh = (const float*)d_in[3];
    const float* re = (const float*)d_in[4];
    float* out = (float*)d_out;
    float* ws = (float*)d_ws;   // needs (16384 + 8*1024)*4 + 4 ~= 98.3 KB

    moe_prep<<<16, 256, 0, stream>>>(gw, ws);
    moe_fused<<<NBLK, 256, 0, stream>>>(x, gb, sh, re, out, ws);
}

// Round 2
// 148.788 us; speedup vs baseline: 1.1742x; 1.1742x over previous
//
#include <hip/hip_runtime.h>

#define NTOK 8192
#define DDIM 1024
#define NEXP 16
#define NPAIR 136   // E*(E+1)/2 pairs with e<=f
#define NREP 16     // s_glob replicas (atomic spread; 64 blocks/replica)
#define XROW 1032   // LDS x-tile row stride in floats (pad 8: 2-way alias only)
#define NBLK 1024   // fused grid size (ticket target)

// ws layout (floats): gwT4 [256*16 float4] = 16384 f | s_glob [NREP*1024] | ticket (1 int)
#define WS_GWT 0
#define WS_SG  16384
#define WS_CNT (WS_SG + NREP * DDIM)   // float-index 32768, used as int slot

// ---------------------------------------------------------------------------
// Prep: transpose gate_w [16][1024] -> gwT4[d4][e] (float4 over d, expert-
// contiguous) so routing reads are fully coalesced. Zeroes s_glob + ticket.
// (End-of-kernel release writes these zero-lines back before moe_fused's
// memside atomics touch them — required for cross-XCD correctness.)
// ---------------------------------------------------------------------------
__global__ __launch_bounds__(256) void moe_prep(
    const float* __restrict__ gate_w,
    float* __restrict__ ws)
{
    const int gid = blockIdx.x * 256 + threadIdx.x;   // 0..4095
    const int e = gid & 15;
    const int d4 = gid >> 4;                          // 0..255
    const float4* gw4 = (const float4*)gate_w;
    float4* gwT4 = (float4*)(ws + WS_GWT);
    gwT4[d4 * 16 + e] = gw4[e * 256 + d4];
    float* s_glob = ws + WS_SG;
    s_glob[gid]         = 0.f;
    s_glob[gid + 4096]  = 0.f;
    s_glob[gid + 8192]  = 0.f;
    s_glob[gid + 12288] = 0.f;
    if (gid == 0) ((int*)ws)[WS_CNT] = 0;             // ticket counter
}

// ---------------------------------------------------------------------------
// Fused: 1024 blocks x 256 thr, 8 tokens/block.
// A: x-tile -> LDS (coalesced, once); thread t owns d-cols 4t..4t+3 ->
//    x^2 column partials with no reduction needed.
// A': x^2 atomics issued HERE (early) — completion hides under B/C/D, so the
//    pre-ticket barrier's vmcnt(0) drain is free. No per-block threadfence:
//    atomics execute at the device coherence point, so barrier-drain + ticket
//    atomic is a sufficient release chain (no L2 writeback needed).
// B: routing from LDS x (broadcast) + gwT (coalesced).
// C: top2 shfl scan (stable, matches lax.top_k).
// D: combine; x from LDS, re rows L1-hot, coalesced float4 out.
// E: ticket; last block acquires (single __threadfence) and computes the
//    diversity loss from s_glob + L2-hot re.
// ---------------------------------------------------------------------------
__global__ __launch_bounds__(256, 4) void moe_fused(
    const float* __restrict__ x,
    const float* __restrict__ gate_b,
    const float* __restrict__ sh,
    const float* __restrict__ re,
    float* __restrict__ out,
    float* __restrict__ ws)
{
    __shared__ __align__(16) float xt[8][XROW];
    __shared__ float nr[NEXP];
    __shared__ float lsum;
    __shared__ int   is_last;

    const int t = threadIdx.x;
    const int b = blockIdx.x;
    const float4* gwT4 = (const float4*)(ws + WS_GWT);
    float* s_glob = ws + WS_SG;

    // ---- A: stage 8 token rows, accumulate x^2 for owned d-columns ----
    float4 ss = make_float4(0.f, 0.f, 0.f, 0.f);
    {
        const float4* x4 = (const float4*)x + (size_t)b * 2048;
        #pragma unroll
        for (int i = 0; i < 8; ++i) {
            float4 v = x4[i * 256 + t];
            *(float4*)&xt[i][4 * t] = v;
            ss.x = fmaf(v.x, v.x, ss.x);
            ss.y = fmaf(v.y, v.y, ss.y);
            ss.z = fmaf(v.z, v.z, ss.z);
            ss.w = fmaf(v.w, v.w, ss.w);
        }
    }
    __syncthreads();

    // ---- A': fire-and-forget x^2 partials (thread owns its 4 d-columns) ----
    {
        float* rep = s_glob + (size_t)(b & (NREP - 1)) * DDIM;
        atomicAdd(&rep[4 * t + 0], ss.x);
        atomicAdd(&rep[4 * t + 1], ss.y);
        atomicAdd(&rep[4 * t + 2], ss.z);
        atomicAdd(&rep[4 * t + 3], ss.w);
    }

    const int lane = t & 63;
    const int wave = t >> 6;
    const int e = lane & 15;
    const int h = (lane >> 4) & 1;
    const int g = lane >> 5;

    // ---- B: routing ----
    const int tokL = wave * 2 + g;
    const float* xrow = &xt[tokL][h * 512];
    const float4* gt = gwT4 + h * 128 * 16;
    float4 a4 = make_float4(0.f, 0.f, 0.f, 0.f);
    #pragma unroll 8
    for (int i = 0; i < 128; ++i) {
        float4 xv = *(const float4*)(xrow + 4 * i);  // 4 distinct addrs, bcast
        float4 gv = gt[i * 16 + e];                  // 256B contiguous / 16 lanes
        a4.x = fmaf(xv.x, gv.x, a4.x);
        a4.y = fmaf(xv.y, gv.y, a4.y);
        a4.z = fmaf(xv.z, gv.z, a4.z);
        a4.w = fmaf(xv.w, gv.w, a4.w);
    }
    float acc = (a4.x + a4.y) + (a4.z + a4.w);
    acc += __shfl_xor(acc, 16, 64);                  // merge d-halves
    acc += gate_b[e];

    // ---- C: stable top2 scan in this token's 16 expert lanes ----
    float v0 = -3.0e38f, v1 = -3.0e38f;
    int i0 = 0, i1 = 0;
    const int base = lane & 32;
    #pragma unroll
    for (int j = 0; j < NEXP; ++j) {
        float lv = __shfl(acc, base + j, 64);
        if (lv > v0)      { v1 = v0; i1 = i0; v0 = lv; i0 = j; }
        else if (lv > v1) { v1 = lv; i1 = j; }
    }
    float ex = __expf(v1 - v0);                      // softmax denom cancels
    float w0 = 1.f / (1.f + ex);
    float w1 = ex * w0;

    // hoisted shared-expert column sum for combine slots
    float4 shs[4];
    {
        const float4* s0 = (const float4*)sh;
        const float4* s1 = (const float4*)(sh + DDIM);
        #pragma unroll
        for (int j = 0; j < 4; ++j) {
            float4 p = s0[lane + 64 * j];
            float4 q = s1[lane + 64 * j];
            shs[j] = make_float4(p.x + q.x, p.y + q.y, p.z + q.z, p.w + q.w);
        }
    }

    // ---- D: combine (x from LDS, coalesced out) ----
    #pragma unroll
    for (int tk = 0; tk < 2; ++tk) {
        const int src = tk << 5;
        float a0 = __shfl(w0, src, 64);
        float a1 = __shfl(w1, src, 64);
        int   e0 = __shfl(i0, src, 64);
        int   e1 = __shfl(i1, src, 64);
        const int tokL2 = wave * 2 + tk;
        const float4* xr = (const float4*)&xt[tokL2][0];
        const float4* r0 = (const float4*)(re + (size_t)e0 * DDIM);
        const float4* r1 = (const float4*)(re + (size_t)e1 * DDIM);
        float4* o = (float4*)(out + ((size_t)b * 8 + tokL2) * DDIM);
        #pragma unroll
        for (int j = 0; j < 4; ++j) {
            float4 xv = xr[lane + 64 * j];
            float4 b0 = r0[lane + 64 * j];
            float4 b1 = r1[lane + 64 * j];
            float4 r;
            r.x = xv.x * (shs[j].x + a0 * b0.x + a1 * b1.x);
            r.y = xv.y * (shs[j].y + a0 * b0.y + a1 * b1.y);
            r.z = xv.z * (shs[j].z + a0 * b0.z + a1 * b1.z);
            r.w = xv.w * (shs[j].w + a0 * b0.w + a1 * b1.w);
            o[lane + 64 * j] = r;
        }
    }

    // ---- E: ticket; last block computes diversity loss ----
    // Barrier implies vmcnt(0): this block's s_glob atomics (issued at A',
    // long since queued) are complete at the coherence point.
    __syncthreads();
    if (t == 0) {
        int tk = atomicAdd((int*)ws + WS_CNT, 1);
        is_last = (tk == NBLK - 1);
    }
    __syncthreads();
    if (!is_last) return;
    __threadfence();   // acquire (last block only): invalidate before reading s_glob

    float* smem = &xt[0][0];                     // xt is dead now; reuse as s_loc
    {
        const float4* sg4 = (const float4*)s_glob;
        float4 a = sg4[t];
        #pragma unroll
        for (int r = 1; r < NREP; ++r) {
            float4 v = sg4[r * 256 + t];
            a.x += v.x; a.y += v.y; a.z += v.z; a.w += v.w;
        }
        ((float4*)smem)[t] = a;                  // s_loc[4t..4t+3]
    }
    if (t == 0) lsum = 0.f;
    __syncthreads();

    float gacc = 0.f;
    int pe = 0, pf = 0;
    if (t < NPAIR) {
        int rem = t;
        while (rem >= NEXP - pe) { rem -= NEXP - pe; ++pe; }
        pf = pe + rem;
        const float4* ra = (const float4*)(re + (size_t)pe * DDIM);   // L2-hot
        const float4* rb = (const float4*)(re + (size_t)pf * DDIM);
        const float4* sl = (const float4*)smem;                       // bcast reads
        #pragma unroll 4
        for (int i = 0; i < 256; ++i) {
            float4 s = sl[i];
            float4 u = ra[i];
            float4 v = rb[i];
            gacc = fmaf(s.x * u.x, v.x, gacc);
            gacc = fmaf(s.y * u.y, v.y, gacc);
            gacc = fmaf(s.z * u.z, v.z, gacc);
            gacc = fmaf(s.w * u.w, v.w, gacc);
        }
        if (pe == pf) nr[pe] = fmaxf(sqrtf(gacc), 1e-8f);
    }
    __syncthreads();
    if (t < NPAIR && pe != pf) {
        float sim = gacc / (nr[pe] * nr[pf]);
        sim = fminf(1.f, fmaxf(-1.f, sim));
        atomicAdd(&lsum, 2.f * sim);             // LDS atomic, 120 adds
    }
    __syncthreads();
    if (t == 0)
        out[(size_t)NTOK * DDIM] = lsum / (float)(NEXP * (NEXP - 1)) * 0.1f;
}

extern "C" void kernel_launch(void* const* d_in, const int* in_sizes, int n_in,
                              void* d_out, int out_size, void* d_ws, size_t ws_size,
                              hipStream_t stream) {
    const float* x  = (const float*)d_in[0];
    const float* gw = (const float*)d_in[1];
    const float* gb = (const float*)d_in[2];
    const float* sh = (const float*)d_in[3];
    const float* re = (const float*)d_in[4];
    float* out = (float*)d_out;
    float* ws = (float*)d_ws;   // needs (16384 + 16*1024)*4 + 4 ~= 131 KB

    moe_prep<<<16, 256, 0, stream>>>(gw, ws);
    moe_fused<<<NBLK, 256, 0, stream>>>(x, gb, sh, re, out, ws);
}